// Round 5
// baseline (362.419 us; speedup 1.0000x reference)
//
#include <hip/hip_runtime.h>
#include <hip/hip_bf16.h>
#include <stdint.h>

// Problem constants (fixed by the reference file)
#define NB 8     // batch
#define NS 2048  // sequence
#define ND 1536  // model dim (K)
#define NT 2048  // padded tracks (N)
#define NH 8     // heads
#define NK2 (ND / 64)  // 24 K-iterations at BK=64

// NUM_TRACKS = [128,256,512,1024,2048,64,32,1024] -> ceil(nt/128) (in 128-tiles)
__constant__ int c_tiles[NH] = {1, 2, 4, 8, 16, 1, 1, 8};

typedef short bf16x8 __attribute__((ext_vector_type(8)));  // 8 bf16 (4 VGPRs)
typedef unsigned short u16x8 __attribute__((ext_vector_type(8)));
typedef float f32x4 __attribute__((ext_vector_type(4)));

__device__ __forceinline__ unsigned short f2bf(float f) {
    union { float f; unsigned u; } a; a.f = f;
    unsigned r = a.u + 0x7fffu + ((a.u >> 16) & 1u);  // RNE
    return (unsigned short)(r >> 16);
}

// ---------------- Fused prepass: x fp32->bf16  +  W transpose+convert -------
#define XBLK 24576
__global__ void cvt_kernel(const float* __restrict__ x,
                           const float* __restrict__ W,
                           const int* __restrict__ hidx,
                           unsigned short* __restrict__ xb,
                           unsigned short* __restrict__ Wt) {
    const int bid = blockIdx.x;
    const int tid = threadIdx.x;
    if (bid < XBLK) {
        const size_t i = (size_t)bid * 256 + tid;  // float4 index
        float4 v = ((const float4*)x)[i];
        ushort4 o;
        o.x = f2bf(v.x); o.y = f2bf(v.y); o.z = f2bf(v.z); o.w = f2bf(v.w);
        ((ushort4*)xb)[i] = o;
        return;
    }
    // W transpose: wid -> (t-tile 32, d-tile 24, h 8)
    const int wid = bid - XBLK;
    const int h = wid / (32 * 24);
    const int rem = wid % (32 * 24);
    const int t0 = (rem % 32) * 64;
    const int d0 = (rem / 32) * 64;
    bool used = false;
    for (int i = 0; i < NB; ++i) used |= (hidx[i] == h);
    if (!used || t0 >= c_tiles[h] * 128) return;

    __shared__ float tile[64][69];  // [d][t], padded
#pragma unroll
    for (int i = 0; i < 4; ++i) {
        const int idx = tid + i * 256;  // 1024 float4 chunks
        const int d = idx >> 4, c = (idx & 15) * 4;
        float4 v = *(const float4*)&W[((size_t)h * ND + d0 + d) * NT + t0 + c];
        tile[d][c] = v.x; tile[d][c + 1] = v.y;
        tile[d][c + 2] = v.z; tile[d][c + 3] = v.w;
    }
    __syncthreads();
    const int t = tid >> 2, dc = (tid & 3) * 16;  // 16 bf16 = 32 B per thread
    u16x8 o0, o1;
#pragma unroll
    for (int j = 0; j < 8; ++j) o0[j] = f2bf(tile[dc + j][t]);
#pragma unroll
    for (int j = 0; j < 8; ++j) o1[j] = f2bf(tile[dc + 8 + j][t]);
    unsigned short* p = Wt + ((size_t)h * NT + t0 + t) * ND + d0 + dc;
    *(u16x8*)p = o0;
    *(u16x8*)(p + 8) = o1;
}

// ---------------- GEMM: out[b] = x[b] @ W[h(b)] + bias[h(b)] ----------------
// 128x128 tile, 4 waves, BK=64. A: GLDS-staged, XOR-swizzled LDS, double-
// buffered. B: DIRECT global->register fragments (bypasses LDS entirely; B
// panels are L2/L3-hot since 16 m-blocks share each panel). Depth-2 counted
// vmcnt: per tile window issue {A:4 GLDS + B:8 reg loads}, WAITV(12) drains
// exactly the PREVIOUS window. LDS traffic per CU/iter drops ~50% (was the
// bottleneck: 192 KB/CU/iter ~ 1500+ cyc vs 310 cyc MFMA).
// T1: bijective XCD chunk-swizzle (m204) keeps A panels XCD-L2-resident.
#define GLDS(g, l)                                                      \
    __builtin_amdgcn_global_load_lds(                                   \
        (const __attribute__((address_space(1))) void*)(g),             \
        (__attribute__((address_space(3))) void*)(l), 16, 0, 0)

#define BAR()                                                           \
    do {                                                                \
        asm volatile("" ::: "memory");                                  \
        __builtin_amdgcn_s_barrier();                                   \
        asm volatile("" ::: "memory");                                  \
    } while (0)
#define WAITV(N) asm volatile("s_waitcnt vmcnt(" #N ")" ::: "memory")

__global__ __launch_bounds__(256) void gemm_kernel(
    const unsigned short* __restrict__ xb,   // bf16 [NB][NS][ND]
    const unsigned short* __restrict__ wt,   // bf16 [NH][NT][ND]
    const float* __restrict__ bias,          // fp32 [NH][NT]
    const int* __restrict__ hidx,            // [NB]
    float* __restrict__ out)                 // fp32 [NB][NS][NT]
{
    const int tid = threadIdx.x;
    const int id = blockIdx.x;

    int hh[NB], tl[NB];
    int P = 0;
#pragma unroll
    for (int b = 0; b < NB; ++b) {
        hh[b] = hidx[b];
        tl[b] = c_tiles[hh[b]];
        P += tl[b];
    }
    const int C = 16 * P;

    int batch, m0, n0;
    if (id >= C) {
        // ---- zero tile: 128x128 of exact zeros ----
        const int Pz = 128 - P;
        const int z = id - C;
        int p = z % Pz;
        const int m = z / Pz;
        int b = 0;
        while (p >= 16 - tl[b]) { p -= 16 - tl[b]; ++b; }
        batch = b; n0 = (tl[b] + p) * 128; m0 = m * 128;
        float* outb = out + (size_t)batch * NS * NT;
        const int row = tid >> 1;
        const int c0 = (tid & 1) * 64;
        float4 zv = make_float4(0.f, 0.f, 0.f, 0.f);
        float4* ptr = (float4*)(outb + (size_t)(m0 + row) * NT + (n0 + c0));
#pragma unroll
        for (int j = 0; j < 16; ++j) ptr[j] = zv;
        return;
    }
    {
        // T1: bijective chunk-swizzle over [0, C): XCD k owns a contiguous
        // logical range -> consecutive m-panels stay in one XCD's L2.
        const int q8 = C >> 3, r8 = C & 7;
        const int xcd = id & 7, i8 = id >> 3;
        const int sid = (xcd < r8 ? xcd * (q8 + 1) : r8 * (q8 + 1) + (xcd - r8) * q8) + i8;
        int p = sid % P;
        const int m = sid / P;
        int b = 0;
        while (p >= tl[b]) { p -= tl[b]; ++b; }
        batch = b; n0 = p * 128; m0 = m * 128;
    }
    const int h = hh[batch];
    float* outb = out + (size_t)batch * NS * NT;

    // A-only LDS, double-buffered: 2 x 16 KiB = 32 KiB
    __shared__ unsigned short As[2][128 * 64];  // [m][k], k-chunks XOR-swizzled

    const int lane = tid & 63;
    const int wave = tid >> 6;         // 0..3
    const int wm = (wave >> 1) * 64;   // 2 m-waves over 128 rows
    const int wn = (wave & 1) * 64;    // 2 n-waves over 128 cols
    const int fr = lane & 15;
    const int q = lane >> 4;           // k-group 0..3

    // A staging: 1024 16B chunks (4/thread).
    // LDS slot c=(row,sc) holds global k-chunk gc = sc ^ (row&7)  [bank swizzle]
    const unsigned short* ga[4];
    int ca[4];
#pragma unroll
    for (int j = 0; j < 4; ++j) {
        const int c = tid + 256 * j;
        const int r = c >> 3, gc = (c & 7) ^ (r & 7);
        ga[j] = xb + ((size_t)batch * NS + m0 + r) * ND + gc * 8;
        ca[j] = c * 8;
    }

    // B direct-from-global fragment bases: lane reads row n0+wn+ni*16+fr at
    // k-chunk (q + kk*4), i.e. shorts offset t*64 + kk*32 + q*8 for tile t.
    const unsigned short* gB[4];
#pragma unroll
    for (int ni = 0; ni < 4; ++ni)
        gB[ni] = wt + ((size_t)h * NT + n0 + wn + ni * 16 + fr) * ND + q * 8;

    // Reader-side swizzled k-offsets (shorts) for kk=0 / kk=1 A sub-tiles.
    const int sw0 = ((q) ^ (fr & 7)) * 8;
    const int sw1 = ((q + 4) ^ (fr & 7)) * 8;

    f32x4 acc[4][4] = {};
    bf16x8 rb0[2][4], rb1[2][4];  // B fragments [kk][ni], two tile buffers

#define PREFA(B)                                                      \
    do {                                                              \
        _Pragma("unroll")                                             \
        for (int j = 0; j < 4; ++j) GLDS(ga[j], &As[B][ca[j]]);       \
        _Pragma("unroll")                                             \
        for (int j = 0; j < 4; ++j) ga[j] += 64;                      \
    } while (0)

#define LOADB(R)                                                      \
    do {                                                              \
        _Pragma("unroll")                                             \
        for (int kk = 0; kk < 2; ++kk)                                \
            _Pragma("unroll")                                         \
            for (int ni = 0; ni < 4; ++ni)                            \
                R[kk][ni] = *(const bf16x8*)(gB[ni] + kk * 32);       \
        _Pragma("unroll")                                             \
        for (int ni = 0; ni < 4; ++ni) gB[ni] += 64;                  \
    } while (0)

#define COMPUTE(B, R)                                                         \
    do {                                                                      \
        _Pragma("unroll")                                                     \
        for (int kk = 0; kk < 2; ++kk) {                                      \
            const int sw = kk ? sw1 : sw0;                                    \
            bf16x8 af[4];                                                     \
            _Pragma("unroll")                                                 \
            for (int mi = 0; mi < 4; ++mi)                                    \
                af[mi] = *(const bf16x8*)(&As[B][(wm + mi * 16 + fr) * 64 + sw]); \
            _Pragma("unroll")                                                 \
            for (int mi = 0; mi < 4; ++mi)                                    \
                _Pragma("unroll")                                             \
                for (int ni = 0; ni < 4; ++ni)                                \
                    acc[mi][ni] = __builtin_amdgcn_mfma_f32_16x16x32_bf16(    \
                        af[mi], R[kk][ni], acc[mi][ni], 0, 0, 0);             \
        }                                                                     \
    } while (0)

    // Prologue: windows for tiles 0 and 1 in flight (12 ops each);
    // WAITV(12) drains tile 0's window, barrier publishes As[0].
    PREFA(0); LOADB(rb0);
    PREFA(1); LOADB(rb1);
    WAITV(12);
    BAR();

    // 22 pipelined tiles (11 unrolled pairs, static buffer indices).
    // Per tile: COMPUTE(cur); barrier (As[cur] read-safe to overwrite);
    // issue tile t+2 window into cur; WAITV(12) -> tile t+1's A+B landed;
    // barrier publishes As[t+1].
    for (int it = 0; it < 11; ++it) {
        COMPUTE(0, rb0);
        BAR();
        PREFA(0); LOADB(rb0);
        WAITV(12);
        BAR();
        COMPUTE(1, rb1);
        BAR();
        PREFA(1); LOADB(rb1);
        WAITV(12);
        BAR();
    }
    // Tail: tile 22 (already published), then drain tile 23 and compute it.
    COMPUTE(0, rb0);
    WAITV(0);
    BAR();
    COMPUTE(1, rb1);

#undef PREFA
#undef LOADB
#undef COMPUTE

    // Epilogue: C/D layout col=lane&15, row=(lane>>4)*4+reg
    float bv[4];
#pragma unroll
    for (int ni = 0; ni < 4; ++ni)
        bv[ni] = bias[(size_t)h * NT + n0 + wn + ni * 16 + fr];

    const int rbase = m0 + wm + q * 4;
#pragma unroll
    for (int mi = 0; mi < 4; ++mi) {
#pragma unroll
        for (int r = 0; r < 4; ++r) {
            float* op = outb + (size_t)(rbase + mi * 16 + r) * NT + n0 + wn + fr;
#pragma unroll
            for (int ni = 0; ni < 4; ++ni)
                op[ni * 16] = acc[mi][ni][r] + bv[ni];
        }
    }
}

extern "C" void kernel_launch(void* const* d_in, const int* in_sizes, int n_in,
                              void* d_out, int out_size, void* d_ws, size_t ws_size,
                              hipStream_t stream) {
    const float* x    = (const float*)d_in[0];  // [NB][NS][ND] fp32
    const int*   hidx = (const int*)d_in[1];    // [NB] int32
    const float* W    = (const float*)d_in[2];  // [NH][ND][NT] fp32
    const float* bias = (const float*)d_in[3];  // [NH][NT] fp32
    float* out = (float*)d_out;

    unsigned short* xb = (unsigned short*)d_ws;            // 48 MiB bf16 x
    unsigned short* wt = xb + (size_t)NB * NS * ND;        // 48 MiB bf16 W^T

    // Fused convert: 24576 x-blocks + 6144 W-blocks
    cvt_kernel<<<dim3(XBLK + 32 * 24 * NH), dim3(256), 0, stream>>>(
        x, W, hidx, xb, wt);
    // GEMM: 2048 blocks = 16 m-tiles x 16 n-tiles x 8 batches, balanced decode
    gemm_kernel<<<dim3(2048), dim3(256), 0, stream>>>(xb, wt, bias, hidx, out);
}

// Round 6
// 353.886 us; speedup vs baseline: 1.0241x; 1.0241x over previous
//
#include <hip/hip_runtime.h>
#include <hip/hip_bf16.h>
#include <stdint.h>

// Problem constants (fixed by the reference file)
#define NB 8     // batch
#define NS 2048  // sequence
#define ND 1536  // model dim (K)
#define NT 2048  // padded tracks (N)
#define NH 8     // heads
#define NKT 48   // 48 K-tiles at BK=32

// NUM_TRACKS = [128,256,512,1024,2048,64,32,1024] -> ceil(nt/128) (in 128-tiles)
__constant__ int c_tiles[NH] = {1, 2, 4, 8, 16, 1, 1, 8};

typedef short bf16x8 __attribute__((ext_vector_type(8)));  // 8 bf16 (4 VGPRs)
typedef unsigned short u16x8 __attribute__((ext_vector_type(8)));
typedef float f32x4 __attribute__((ext_vector_type(4)));

__device__ __forceinline__ unsigned short f2bf(float f) {
    union { float f; unsigned u; } a; a.f = f;
    unsigned r = a.u + 0x7fffu + ((a.u >> 16) & 1u);  // RNE
    return (unsigned short)(r >> 16);
}

// ---------------- Fused prepass: x fp32->bf16  +  W transpose+convert -------
#define XBLK 24576
__global__ void cvt_kernel(const float* __restrict__ x,
                           const float* __restrict__ W,
                           const int* __restrict__ hidx,
                           unsigned short* __restrict__ xb,
                           unsigned short* __restrict__ Wt) {
    const int bid = blockIdx.x;
    const int tid = threadIdx.x;
    if (bid < XBLK) {
        const size_t i = (size_t)bid * 256 + tid;  // float4 index
        float4 v = ((const float4*)x)[i];
        ushort4 o;
        o.x = f2bf(v.x); o.y = f2bf(v.y); o.z = f2bf(v.z); o.w = f2bf(v.w);
        ((ushort4*)xb)[i] = o;
        return;
    }
    // W transpose: wid -> (t-tile 32, d-tile 24, h 8)
    const int wid = bid - XBLK;
    const int h = wid / (32 * 24);
    const int rem = wid % (32 * 24);
    const int t0 = (rem % 32) * 64;
    const int d0 = (rem / 32) * 64;
    bool used = false;
    for (int i = 0; i < NB; ++i) used |= (hidx[i] == h);
    if (!used || t0 >= c_tiles[h] * 128) return;

    __shared__ float tile[64][69];  // [d][t], padded
#pragma unroll
    for (int i = 0; i < 4; ++i) {
        const int idx = tid + i * 256;  // 1024 float4 chunks
        const int d = idx >> 4, c = (idx & 15) * 4;
        float4 v = *(const float4*)&W[((size_t)h * ND + d0 + d) * NT + t0 + c];
        tile[d][c] = v.x; tile[d][c + 1] = v.y;
        tile[d][c + 2] = v.z; tile[d][c + 3] = v.w;
    }
    __syncthreads();
    const int t = tid >> 2, dc = (tid & 3) * 16;  // 16 bf16 = 32 B per thread
    u16x8 o0, o1;
#pragma unroll
    for (int j = 0; j < 8; ++j) o0[j] = f2bf(tile[dc + j][t]);
#pragma unroll
    for (int j = 0; j < 8; ++j) o1[j] = f2bf(tile[dc + 8 + j][t]);
    unsigned short* p = Wt + ((size_t)h * NT + t0 + t) * ND + d0 + dc;
    *(u16x8*)p = o0;
    *(u16x8*)(p + 8) = o1;
}

// ---------------- GEMM: out[b] = x[b] @ W[h(b)] + bias[h(b)] ----------------
// 128x128 tile, 4 waves, BK=32, XOR-swizzled LDS, depth-2 counted-vmcnt
// pipeline (Round-4 proven schedule, geometry only changed). LDS shrinks
// 64->32 KB so up to 5 blocks/CU are resident (was the binder: 2 blocks/CU,
// occupancy 15.5%, iter_time ~1700cyc vs 320cyc MFMA; m103 proves this wave
// structure reaches 912 TF at ~3 blocks/CU via cross-block TLP).
// T5: s_setprio(1) around the MFMA cluster (role-split schedule -> m224).
// T1: bijective XCD chunk-swizzle keeps A panels XCD-L2-resident.
#define GLDS(g, l)                                                      \
    __builtin_amdgcn_global_load_lds(                                   \
        (const __attribute__((address_space(1))) void*)(g),             \
        (__attribute__((address_space(3))) void*)(l), 16, 0, 0)

#define BAR()                                                           \
    do {                                                                \
        asm volatile("" ::: "memory");                                  \
        __builtin_amdgcn_s_barrier();                                   \
        asm volatile("" ::: "memory");                                  \
    } while (0)
#define WAITV(N) asm volatile("s_waitcnt vmcnt(" #N ")" ::: "memory")

__global__ __launch_bounds__(256) void gemm_kernel(
    const unsigned short* __restrict__ xb,   // bf16 [NB][NS][ND]
    const unsigned short* __restrict__ wt,   // bf16 [NH][NT][ND]
    const float* __restrict__ bias,          // fp32 [NH][NT]
    const int* __restrict__ hidx,            // [NB]
    float* __restrict__ out)                 // fp32 [NB][NS][NT]
{
    const int tid = threadIdx.x;
    const int id = blockIdx.x;

    int hh[NB], tl[NB];
    int P = 0;
#pragma unroll
    for (int b = 0; b < NB; ++b) {
        hh[b] = hidx[b];
        tl[b] = c_tiles[hh[b]];
        P += tl[b];
    }
    const int C = 16 * P;

    int batch, m0, n0;
    if (id >= C) {
        // ---- zero tile: 128x128 of exact zeros ----
        const int Pz = 128 - P;
        const int z = id - C;
        int p = z % Pz;
        const int m = z / Pz;
        int b = 0;
        while (p >= 16 - tl[b]) { p -= 16 - tl[b]; ++b; }
        batch = b; n0 = (tl[b] + p) * 128; m0 = m * 128;
        float* outb = out + (size_t)batch * NS * NT;
        const int row = tid >> 1;
        const int c0 = (tid & 1) * 64;
        float4 zv = make_float4(0.f, 0.f, 0.f, 0.f);
        float4* ptr = (float4*)(outb + (size_t)(m0 + row) * NT + (n0 + c0));
#pragma unroll
        for (int j = 0; j < 16; ++j) ptr[j] = zv;
        return;
    }
    {
        // T1: bijective chunk-swizzle over [0, C): XCD k owns a contiguous
        // logical range -> consecutive m-panels stay in one XCD's L2.
        const int q8 = C >> 3, r8 = C & 7;
        const int xcd = id & 7, i8 = id >> 3;
        const int sid = (xcd < r8 ? xcd * (q8 + 1) : r8 * (q8 + 1) + (xcd - r8) * q8) + i8;
        int p = sid % P;
        const int m = sid / P;
        int b = 0;
        while (p >= tl[b]) { p -= tl[b]; ++b; }
        batch = b; n0 = p * 128; m0 = m * 128;
    }
    const int h = hh[batch];
    float* outb = out + (size_t)batch * NS * NT;

    // Double-buffered LDS at BK=32: 2 x (8 KiB A + 8 KiB B) = 32 KiB
    __shared__ unsigned short As[2][128 * 32];  // [m][k], k-chunks XOR-swizzled
    __shared__ unsigned short Bs[2][128 * 32];  // [n][k] (B^T), swizzled

    const int lane = tid & 63;
    const int wave = tid >> 6;         // 0..3
    const int wm = (wave >> 1) * 64;   // 2 m-waves over 128 rows
    const int wn = (wave & 1) * 64;    // 2 n-waves over 128 cols
    const int fr = lane & 15;
    const int q = lane >> 4;           // k-group 0..3

    // Staging: A = 512 16B chunks (2/thread), B = 512 (2/thread).
    // LDS slot c=(row,sc) holds global k-chunk gc = sc ^ (row&3)  [bank swizzle]
    const unsigned short* ga[2];
    const unsigned short* gb[2];
    int ca[2], cb[2];
#pragma unroll
    for (int j = 0; j < 2; ++j) {
        const int c = tid + 256 * j;
        const int r = c >> 2, gc = (c & 3) ^ (r & 3);
        ga[j] = xb + ((size_t)batch * NS + m0 + r) * ND + gc * 8;
        ca[j] = c * 8;
        gb[j] = wt + ((size_t)h * NT + n0 + r) * ND + gc * 8;
        cb[j] = c * 8;
    }

    // Reader-side swizzled k-offset (shorts): lane (fr,q) reads k-chunk q at
    // row R; stored slot = q ^ (R&3) = q ^ (fr&3) since wm, mi*16 are %4==0.
    const int sw = (q ^ (fr & 3)) * 8;

    f32x4 acc[4][4] = {};

#define PREFETCH(B)                                                   \
    do {                                                              \
        _Pragma("unroll")                                             \
        for (int j = 0; j < 2; ++j) GLDS(ga[j], &As[B][ca[j]]);       \
        _Pragma("unroll")                                             \
        for (int j = 0; j < 2; ++j) GLDS(gb[j], &Bs[B][cb[j]]);       \
        _Pragma("unroll")                                             \
        for (int j = 0; j < 2; ++j) { ga[j] += 32; gb[j] += 32; }     \
    } while (0)

#define COMPUTE(B)                                                           \
    do {                                                                     \
        bf16x8 af[4], bfr[4];                                                \
        _Pragma("unroll")                                                    \
        for (int mi = 0; mi < 4; ++mi)                                       \
            af[mi] = *(const bf16x8*)(&As[B][(wm + mi * 16 + fr) * 32 + sw]); \
        _Pragma("unroll")                                                    \
        for (int ni = 0; ni < 4; ++ni)                                       \
            bfr[ni] = *(const bf16x8*)(&Bs[B][(wn + ni * 16 + fr) * 32 + sw]); \
        __builtin_amdgcn_s_setprio(1);                                       \
        _Pragma("unroll")                                                    \
        for (int mi = 0; mi < 4; ++mi)                                       \
            _Pragma("unroll")                                                \
            for (int ni = 0; ni < 4; ++ni)                                   \
                acc[mi][ni] = __builtin_amdgcn_mfma_f32_16x16x32_bf16(       \
                    af[mi], bfr[ni], acc[mi][ni], 0, 0, 0);                  \
        __builtin_amdgcn_s_setprio(0);                                       \
    } while (0)

    // Prologue: tiles 0 and 1 in flight (4 ops each); WAITV(4) drains tile
    // 0's window (tile 1's 4 loads stay outstanding across the barrier).
    PREFETCH(0);
    PREFETCH(1);
    WAITV(4);
    BAR();

    // 46 pipelined tiles (23 unrolled pairs, static buffer indices).
    // Per tile: COMPUTE(cur); barrier (read-safety); issue tile t+2 into cur;
    // WAITV(4) -> tile t+1 landed (issued one full iteration ago); barrier
    // publishes.
    for (int it = 0; it < 23; ++it) {
        COMPUTE(0);
        BAR();
        PREFETCH(0);
        WAITV(4);
        BAR();
        COMPUTE(1);
        BAR();
        PREFETCH(1);
        WAITV(4);
        BAR();
    }
    // Tail: tile 46 (published), then drain tile 47 and compute it.
    COMPUTE(0);
    WAITV(0);
    BAR();
    COMPUTE(1);

#undef PREFETCH
#undef COMPUTE

    // Epilogue: C/D layout col=lane&15, row=(lane>>4)*4+reg
    float bv[4];
#pragma unroll
    for (int ni = 0; ni < 4; ++ni)
        bv[ni] = bias[(size_t)h * NT + n0 + wn + ni * 16 + fr];

    const int rbase = m0 + wm + q * 4;
#pragma unroll
    for (int mi = 0; mi < 4; ++mi) {
#pragma unroll
        for (int r = 0; r < 4; ++r) {
            float* op = outb + (size_t)(rbase + mi * 16 + r) * NT + n0 + wn + fr;
#pragma unroll
            for (int ni = 0; ni < 4; ++ni)
                op[ni * 16] = acc[mi][ni][r] + bv[ni];
        }
    }
}

extern "C" void kernel_launch(void* const* d_in, const int* in_sizes, int n_in,
                              void* d_out, int out_size, void* d_ws, size_t ws_size,
                              hipStream_t stream) {
    const float* x    = (const float*)d_in[0];  // [NB][NS][ND] fp32
    const int*   hidx = (const int*)d_in[1];    // [NB] int32
    const float* W    = (const float*)d_in[2];  // [NH][ND][NT] fp32
    const float* bias = (const float*)d_in[3];  // [NH][NT] fp32
    float* out = (float*)d_out;

    unsigned short* xb = (unsigned short*)d_ws;            // 48 MiB bf16 x
    unsigned short* wt = xb + (size_t)NB * NS * ND;        // 48 MiB bf16 W^T

    // Fused convert: 24576 x-blocks + 6144 W-blocks
    cvt_kernel<<<dim3(XBLK + 32 * 24 * NH), dim3(256), 0, stream>>>(
        x, W, hidx, xb, wt);
    // GEMM: 2048 blocks = 16 m-tiles x 16 n-tiles x 8 batches, balanced decode
    gemm_kernel<<<dim3(2048), dim3(256), 0, stream>>>(xb, wt, bias, hidx, out);
}

// Round 7
// 318.923 us; speedup vs baseline: 1.1364x; 1.1096x over previous
//
#include <hip/hip_runtime.h>
#include <hip/hip_bf16.h>
#include <stdint.h>

// Problem constants (fixed by the reference file)
#define NB 8     // batch
#define NS 2048  // sequence
#define ND 1536  // model dim (K)
#define NT 2048  // padded tracks (N)
#define NH 8     // heads
#define NK2 (ND / 64)  // 24 K-iterations at BK=64

// NUM_TRACKS = [128,256,512,1024,2048,64,32,1024] -> ceil(nt/128) (in 128-tiles)
__constant__ int c_tiles[NH] = {1, 2, 4, 8, 16, 1, 1, 8};

typedef short bf16x8 __attribute__((ext_vector_type(8)));  // 8 bf16 (4 VGPRs)
typedef unsigned short u16x8 __attribute__((ext_vector_type(8)));
typedef float f32x4 __attribute__((ext_vector_type(4)));

__device__ __forceinline__ unsigned short f2bf(float f) {
    union { float f; unsigned u; } a; a.f = f;
    unsigned r = a.u + 0x7fffu + ((a.u >> 16) & 1u);  // RNE
    return (unsigned short)(r >> 16);
}

// ---------------- Fused prepass: x fp32->bf16  +  W transpose+convert -------
// For heads with odd tile count (128-col heads), Wt rows [tl*128, tl256*256)
// are ZERO-FILLED so the 256-wide GEMM tiles read zeros, matching the
// zero-padded reference weights.
#define XBLK 24576
__global__ void cvt_kernel(const float* __restrict__ x,
                           const float* __restrict__ W,
                           const int* __restrict__ hidx,
                           unsigned short* __restrict__ xb,
                           unsigned short* __restrict__ Wt) {
    const int bid = blockIdx.x;
    const int tid = threadIdx.x;
    if (bid < XBLK) {
        const size_t i = (size_t)bid * 256 + tid;  // float4 index
        float4 v = ((const float4*)x)[i];
        ushort4 o;
        o.x = f2bf(v.x); o.y = f2bf(v.y); o.z = f2bf(v.z); o.w = f2bf(v.w);
        ((ushort4*)xb)[i] = o;
        return;
    }
    // W transpose: wid -> (t-tile 32, d-tile 24, h 8)
    const int wid = bid - XBLK;
    const int h = wid / (32 * 24);
    const int rem = wid % (32 * 24);
    const int t0 = (rem % 32) * 64;
    const int d0 = (rem / 32) * 64;
    bool used = false;
    for (int i = 0; i < NB; ++i) used |= (hidx[i] == h);
    const int tl = c_tiles[h];
    const int tl2 = (tl + 1) >> 1;  // 256-col tiles
    if (!used || t0 >= tl2 * 256) return;
    if (t0 >= tl * 128) {
        // pad panel for odd-tl heads: zero Wt rows [t0, t0+64)
        const int t = tid >> 2, dc = (tid & 3) * 16;
        u16x8 z = {};
        unsigned short* p = Wt + ((size_t)h * NT + t0 + t) * ND + d0 + dc;
        *(u16x8*)p = z;
        *(u16x8*)(p + 8) = z;
        return;
    }

    __shared__ float tile[64][69];  // [d][t], padded
#pragma unroll
    for (int i = 0; i < 4; ++i) {
        const int idx = tid + i * 256;  // 1024 float4 chunks
        const int d = idx >> 4, c = (idx & 15) * 4;
        float4 v = *(const float4*)&W[((size_t)h * ND + d0 + d) * NT + t0 + c];
        tile[d][c] = v.x; tile[d][c + 1] = v.y;
        tile[d][c + 2] = v.z; tile[d][c + 3] = v.w;
    }
    __syncthreads();
    const int t = tid >> 2, dc = (tid & 3) * 16;  // 16 bf16 = 32 B per thread
    u16x8 o0, o1;
#pragma unroll
    for (int j = 0; j < 8; ++j) o0[j] = f2bf(tile[dc + j][t]);
#pragma unroll
    for (int j = 0; j < 8; ++j) o1[j] = f2bf(tile[dc + 8 + j][t]);
    unsigned short* p = Wt + ((size_t)h * NT + t0 + t) * ND + d0 + dc;
    *(u16x8*)p = o0;
    *(u16x8*)(p + 8) = o1;
}

// ---------------- GEMM: out[b] = x[b] @ W[h(b)] + bias[h(b)] ----------------
// 256x256 tile, 8 waves (512 thr), per-wave 128x64, BK=64. Round-4's PROVEN
// depth-2 counted-vmcnt schedule, scaled: per tile {COMPUTE; BAR; PREFETCH
// t+2 (8 GLDS/thread); WAITV(8); BAR}. Rationale: round 4 was STAGING-BW
// bound (503 MB staged / ~6.5 TB/s = 77us ~= measured 80us). 256^2 doubles
// FLOP per staged byte -> ~270 MB staged -> ~41us model.
// XOR swizzle unchanged (128 B row stride, 0 conflicts measured).
// T1: bijective XCD chunk-swizzle. T5: setprio around MFMA clusters.
#define GLDS(g, l)                                                      \
    __builtin_amdgcn_global_load_lds(                                   \
        (const __attribute__((address_space(1))) void*)(g),             \
        (__attribute__((address_space(3))) void*)(l), 16, 0, 0)

#define BAR()                                                           \
    do {                                                                \
        asm volatile("" ::: "memory");                                  \
        __builtin_amdgcn_s_barrier();                                   \
        asm volatile("" ::: "memory");                                  \
    } while (0)
#define WAITV(N) asm volatile("s_waitcnt vmcnt(" #N ")" ::: "memory")

__global__ __launch_bounds__(512, 2) void gemm_kernel(
    const unsigned short* __restrict__ xb,   // bf16 [NB][NS][ND]
    const unsigned short* __restrict__ wt,   // bf16 [NH][NT][ND]
    const float* __restrict__ bias,          // fp32 [NH][NT]
    const int* __restrict__ hidx,            // [NB]
    float* __restrict__ out)                 // fp32 [NB][NS][NT]
{
    const int tid = threadIdx.x;
    const int id = blockIdx.x;

    int hh[NB], tl2[NB];
    int S = 0;
#pragma unroll
    for (int b = 0; b < NB; ++b) {
        hh[b] = hidx[b];
        tl2[b] = (c_tiles[hh[b]] + 1) >> 1;  // 256-col tiles
        S += tl2[b];
    }
    const int C = 8 * S;

    int batch, m0, n0;
    if (id >= C) {
        // ---- zero tile: 256x256 of exact zeros ----
        const int Pz = 64 - S;
        const int z = id - C;
        int p = z % Pz;
        const int m = z / Pz;
        int b = 0;
        while (p >= 8 - tl2[b]) { p -= 8 - tl2[b]; ++b; }
        batch = b; n0 = (tl2[b] + p) * 256; m0 = m * 256;
        float* outb = out + (size_t)batch * NS * NT;
        const int row = tid >> 1;
        const int c0 = (tid & 1) * 128;
        float4 zv = make_float4(0.f, 0.f, 0.f, 0.f);
        float4* ptr = (float4*)(outb + (size_t)(m0 + row) * NT + (n0 + c0));
#pragma unroll
        for (int j = 0; j < 32; ++j) ptr[j] = zv;
        return;
    }
    {
        // T1: bijective chunk-swizzle over [0, C): XCD k owns a contiguous
        // logical range -> consecutive m-panels stay in one XCD's L2.
        const int q8 = C >> 3, r8 = C & 7;
        const int xcd = id & 7, i8 = id >> 3;
        const int sid = (xcd < r8 ? xcd * (q8 + 1) : r8 * (q8 + 1) + (xcd - r8) * q8) + i8;
        int p = sid % S;
        const int m = sid / S;
        int b = 0;
        while (p >= tl2[b]) { p -= tl2[b]; ++b; }
        batch = b; n0 = p * 256; m0 = m * 256;
    }
    const int h = hh[batch];
    float* outb = out + (size_t)batch * NS * NT;

    // Double-buffered LDS: 2 x (32 KiB A + 32 KiB B) = 128 KiB -> 1 block/CU
    __shared__ unsigned short As[2][256 * 64];  // [m][k], k-chunks XOR-swizzled
    __shared__ unsigned short Bs[2][256 * 64];  // [n][k] (B^T), swizzled

    const int lane = tid & 63;
    const int wave = tid >> 6;         // 0..7
    const int wm = (wave >> 2) * 128;  // 2 m-waves over 256 rows
    const int wn = (wave & 3) * 64;    // 4 n-waves over 256 cols
    const int fr = lane & 15;
    const int q = lane >> 4;           // k-group 0..3

    // Staging: A = 2048 16B chunks (4/thread), B = 2048 (4/thread).
    // LDS slot c=(row,sc) holds global k-chunk gc = sc ^ (row&7)  [bank swizzle]
    const unsigned short* ga[4];
    const unsigned short* gb[4];
    int ca[4], cb[4];
#pragma unroll
    for (int j = 0; j < 4; ++j) {
        const int c = tid + 512 * j;
        const int r = c >> 3, gc = (c & 7) ^ (r & 7);
        ga[j] = xb + ((size_t)batch * NS + m0 + r) * ND + gc * 8;
        ca[j] = c * 8;
        gb[j] = wt + ((size_t)h * NT + n0 + r) * ND + gc * 8;
        cb[j] = c * 8;
    }

    // Reader-side swizzled k-offsets (shorts) for kk=0 / kk=1 sub-tiles.
    const int sw0 = ((q) ^ (fr & 7)) * 8;
    const int sw1 = ((q + 4) ^ (fr & 7)) * 8;

    f32x4 acc[8][4] = {};

#define PREFETCH(B)                                                   \
    do {                                                              \
        _Pragma("unroll")                                             \
        for (int j = 0; j < 4; ++j) GLDS(ga[j], &As[B][ca[j]]);       \
        _Pragma("unroll")                                             \
        for (int j = 0; j < 4; ++j) GLDS(gb[j], &Bs[B][cb[j]]);       \
        _Pragma("unroll")                                             \
        for (int j = 0; j < 4; ++j) { ga[j] += 64; gb[j] += 64; }     \
    } while (0)

#define COMPUTE(B)                                                            \
    do {                                                                      \
        _Pragma("unroll")                                                     \
        for (int kk = 0; kk < 2; ++kk) {                                      \
            const int sw = kk ? sw1 : sw0;                                    \
            bf16x8 af[8], bfr[4];                                             \
            _Pragma("unroll")                                                 \
            for (int mi = 0; mi < 8; ++mi)                                    \
                af[mi] = *(const bf16x8*)(&As[B][(wm + mi * 16 + fr) * 64 + sw]); \
            _Pragma("unroll")                                                 \
            for (int ni = 0; ni < 4; ++ni)                                    \
                bfr[ni] = *(const bf16x8*)(&Bs[B][(wn + ni * 16 + fr) * 64 + sw]); \
            __builtin_amdgcn_s_setprio(1);                                    \
            _Pragma("unroll")                                                 \
            for (int mi = 0; mi < 8; ++mi)                                    \
                _Pragma("unroll")                                             \
                for (int ni = 0; ni < 4; ++ni)                                \
                    acc[mi][ni] = __builtin_amdgcn_mfma_f32_16x16x32_bf16(    \
                        af[mi], bfr[ni], acc[mi][ni], 0, 0, 0);               \
            __builtin_amdgcn_s_setprio(0);                                    \
        }                                                                     \
    } while (0)

    // Prologue: tiles 0 and 1 in flight (8 ops each); WAITV(8) drains tile
    // 0's window (tile 1's 8 loads stay outstanding across the barrier).
    PREFETCH(0);
    PREFETCH(1);
    WAITV(8);
    BAR();

    // 22 pipelined tiles (11 unrolled pairs, static buffer indices).
    // Per tile: COMPUTE(cur); barrier (read-safety); issue tile t+2 into cur;
    // WAITV(8) -> tile t+1 landed (issued one full iteration ago); barrier
    // publishes.
    for (int it = 0; it < 11; ++it) {
        COMPUTE(0);
        BAR();
        PREFETCH(0);
        WAITV(8);
        BAR();
        COMPUTE(1);
        BAR();
        PREFETCH(1);
        WAITV(8);
        BAR();
    }
    // Tail: tile 22 (published), then drain tile 23 and compute it.
    COMPUTE(0);
    WAITV(0);
    BAR();
    COMPUTE(1);

#undef PREFETCH
#undef COMPUTE

    // Epilogue: C/D layout col=lane&15, row=(lane>>4)*4+reg
    float bv[4];
#pragma unroll
    for (int ni = 0; ni < 4; ++ni)
        bv[ni] = bias[(size_t)h * NT + n0 + wn + ni * 16 + fr];

    const int rbase = m0 + wm + q * 4;
#pragma unroll
    for (int mi = 0; mi < 8; ++mi) {
#pragma unroll
        for (int r = 0; r < 4; ++r) {
            float* op = outb + (size_t)(rbase + mi * 16 + r) * NT + n0 + wn + fr;
#pragma unroll
            for (int ni = 0; ni < 4; ++ni)
                op[ni * 16] = acc[mi][ni][r] + bv[ni];
        }
    }
}

extern "C" void kernel_launch(void* const* d_in, const int* in_sizes, int n_in,
                              void* d_out, int out_size, void* d_ws, size_t ws_size,
                              hipStream_t stream) {
    const float* x    = (const float*)d_in[0];  // [NB][NS][ND] fp32
    const int*   hidx = (const int*)d_in[1];    // [NB] int32
    const float* W    = (const float*)d_in[2];  // [NH][ND][NT] fp32
    const float* bias = (const float*)d_in[3];  // [NH][NT] fp32
    float* out = (float*)d_out;

    unsigned short* xb = (unsigned short*)d_ws;            // 48 MiB bf16 x
    unsigned short* wt = xb + (size_t)NB * NS * ND;        // 48 MiB bf16 W^T

    // Fused convert: 24576 x-blocks + 6144 W-blocks
    cvt_kernel<<<dim3(XBLK + 32 * 24 * NH), dim3(256), 0, stream>>>(
        x, W, hidx, xb, wt);
    // GEMM: 512 blocks = 8 m-tiles x 8 n-tiles x 8 batches at 256^2
    gemm_kernel<<<dim3(512), dim3(512), 0, stream>>>(xb, wt, bias, hidx, out);
}